// Round 6
// baseline (1510.127 us; speedup 1.0000x reference)
//
#include <hip/hip_runtime.h>
#include <hip/hip_bf16.h>

// Problem constants
constexpr int NB  = 16;     // batch
constexpr int DIN = 512;    // channels
constexpr int TT  = 4096;   // time
constexpr int NCB = 9;      // codebooks
constexpr int KK  = 1024;   // entries per codebook

// output layout (FLOAT32: codes, latent, closs, bloss)
constexpr size_t OUT_LAT   = (size_t)NB * NCB * TT;            // 589824
constexpr size_t OUT_CLOSS = OUT_LAT + (size_t)NB * DIN * TT;  // 34144256

// LDS strides — bank math per 32-lane phase (SIMD-32):
// SRES = 514 (≡2 mod 32): D-phase RMW at col*S+grp+32j -> bank (2c+g) mod 32,
//   all 32 distinct per phase (measured ~0 conflicts). float2-aligned.
// SWIN = 516: float4-aligned staging writes; A1 reads float2.
// Staged-table row pads (floats): chosen so stride*4B %16==0 (b128/b64 align)
//   and stride%32 == 4 -> per-phase grp pair maps to distinct bank clusters.
constexpr int SRES = 514;
constexpr int SWIN = 516;
constexpr int SCBN = 260;   // 256 + 4  (1040B, %16=0, %32=4)
constexpr int SC2  = 36;    // 32 + 4   (144B,  %16=0)
constexpr int SWO  = 132;   // 128 + 4  (528B,  %16=0)
constexpr int SOB  = 20;    // 16 + 4   (80B,   %16=0)

// Scratch as __device__ globals (round-0 postmortem: never trust ws_size).
// Tables TRANSPOSED for the 32-way scan decomposition:
//   k -> [i][k&31][k>>5] so each grp's walk is a sequential stream.
__device__ __align__(16) float g_cbn [NCB * KK * 8];   // [i][grp32][j32][8]
__device__ __align__(16) float g_c2  [NCB * KK];       // [i][grp32][j32]
__device__ __align__(16) float g_win [NCB * 8 * DIN];  // [i][o][c]
__device__ __align__(16) float g_wout[NCB * DIN * 8];  // [i][grp32][j16][8]
__device__ __align__(16) float g_obt [NCB * DIN];      // [i][grp32][j16]
__device__ double g_loss;

// square with forced separate rounding (blocks -ffp-contract=fast fusing the
// mul into a following add — numpy rounds every square before summing)
__device__ __forceinline__ float sqf(float x) {
  float r = x * x;
  asm volatile("" : "+v"(r));
  return r;
}

// ---------- prep: weight-norm for in_proj ----------
// EXACT numpy pairwise_sum(n=512) mirror for ||v||.
__global__ void prep_win_k(const float* __restrict__ in_v, const float* __restrict__ in_g) {
  const int r = blockIdx.x * 64 + threadIdx.x;  // i*8 + o, < 72
  if (r >= NCB * 8) return;
  const float* v = in_v + (size_t)r * DIN;
  float blk[4];
#pragma unroll
  for (int bb = 0; bb < 4; ++bb) {
    const float* a = v + bb * 128;
    float r8[8];
#pragma unroll
    for (int j = 0; j < 8; ++j) r8[j] = sqf(a[j]);
#pragma unroll
    for (int m = 1; m < 16; ++m)
#pragma unroll
      for (int j = 0; j < 8; ++j) r8[j] += sqf(a[m * 8 + j]);
    blk[bb] = ((r8[0] + r8[1]) + (r8[2] + r8[3])) + ((r8[4] + r8[5]) + (r8[6] + r8[7]));
  }
  const float total = (blk[0] + blk[1]) + (blk[2] + blk[3]);
  const float nrm = sqrtf(total);               // IEEE sqrt (HIP default precise)
  const float g = in_g[r];
  float* w = g_win + (size_t)r * DIN;
  for (int c = 0; c < DIN; ++c) w[c] = (g * v[c]) / nrm;  // np: (g*v) rounds, then /
}

// ---------- prep: weight-norm for out_proj (n=8 np tree) + transposed store ----------
__global__ void prep_wout_k(const float* __restrict__ out_v, const float* __restrict__ out_g,
                            const float* __restrict__ out_b) {
  const int row = blockIdx.x * 256 + threadIdx.x;  // i*512 + c, < 4608
  const float* v = out_v + (size_t)row * 8;
  float q[8];
#pragma unroll
  for (int d = 0; d < 8; ++d) q[d] = sqf(v[d]);
  const float nrm = sqrtf(((q[0] + q[1]) + (q[2] + q[3])) + ((q[4] + q[5]) + (q[6] + q[7])));
  const float g = out_g[row];
  const int i = row >> 9, c = row & 511;
  float* w = g_wout + (((size_t)i * 32 + (c & 31)) * 16 + (c >> 5)) * 8;
#pragma unroll
  for (int d = 0; d < 8; ++d) w[d] = (g * v[d]) / nrm;   // values identical, layout transposed
  g_obt[((size_t)i * 32 + (c & 31)) * 16 + (c >> 5)] = out_b[row];
}

// ---------- prep: normalized codebooks + squared norms (transposed); zero loss ----------
__global__ void prep_cbn_k(const float* __restrict__ cb) {
  const int row = blockIdx.x * 256 + threadIdx.x;  // i*1024 + k, < 9216
  const float* v = cb + (size_t)row * 8;
  float q[8];
#pragma unroll
  for (int d = 0; d < 8; ++d) q[d] = sqf(v[d]);
  float nrm = sqrtf(((q[0] + q[1]) + (q[2] + q[3])) + ((q[4] + q[5]) + (q[6] + q[7])));
  nrm = fmaxf(nrm, 1e-12f);
  const int i = row >> 10, k = row & 1023;
  float* dst = g_cbn + (((size_t)i * 32 + (k & 31)) * 32 + (k >> 5)) * 8;
  float cn[8];
#pragma unroll
  for (int d = 0; d < 8; ++d) { cn[d] = v[d] / nrm; dst[d] = cn[d]; }
  float s2[8];
#pragma unroll
  for (int d = 0; d < 8; ++d) s2[d] = sqf(cn[d]);
  g_c2[(size_t)i * 1024 + (k & 31) * 32 + (k >> 5)] =
      ((s2[0] + s2[1]) + (s2[2] + s2[3])) + ((s2[4] + s2[5]) + (s2[6] + s2[7]));
  if (row == 0) g_loss = 0.0;
}

// ---------- main fused RVQ chain ----------
// Round-6: WAVE-SPECIALIZED STAGING. While waves 0-1 (tid<128) run the
// bit-pinned A1 serial chains, waves 2-7 (384 threads) stage this iteration's
// codebook+c2+W_out+bias into padded LDS and prefetch W_in(i+1) into a double
// buffer. B and D then run issue-bound from LDS (rounds 3-5: occupancy and
// reg-pipelining both null -> limiter was L2-latency-exposed table streams +
// idle CU during A1). LDS ~122KB -> 1 block/CU by design. Arithmetic is
// bit-identical to round 4 (passed).
__global__ __launch_bounds__(512, 2)
void rvq_main_k(const float* __restrict__ z, const float* __restrict__ in_b,
                const float* __restrict__ cb, float* __restrict__ out) {
  __shared__ __align__(16) float s_res [16 * SRES];     // residual [col][c]
  __shared__ __align__(16) float s_win [2 * 8 * SWIN];  // W_in dbuf [buf][o][c]
  __shared__ __align__(16) float s_cbn [32 * SCBN];     // staged cbn [grp][j32*8]
  __shared__ __align__(16) float s_c2  [32 * SC2];      // staged c2  [grp][j32]
  __shared__ __align__(16) float s_wout[32 * SWO];      // staged wout [grp][j16*8]
  __shared__ __align__(16) float s_obt [32 * SOB];      // staged bias [grp][j16]
  __shared__ float s_ze[128];   // z_e [d][col]
  __shared__ float s_en[128];   // enc_n [d][col]
  __shared__ float s_s[16];     // sum(enc_n^2) per col
  __shared__ float s_cd[128];   // per-wave best dist [wave8][col]
  __shared__ int   s_ck[128];   // per-wave best k

  const int tid = threadIdx.x;
  const int col = tid & 15;
  const int grp = tid >> 4;     // 0..31
  const int b   = blockIdx.x >> 8;
  const int t0  = (blockIdx.x & 255) << 4;

  // init: residual = z in LDS; latent accumulator lr = 0 in registers.
  float lr[16];
  {
    const float* zb = z + (size_t)b * DIN * TT + t0 + col;
#pragma unroll
    for (int j = 0; j < 16; ++j) {
      const int c = grp + (j << 5);
      s_res[col * SRES + c] = zb[(size_t)c * TT];
      lr[j] = 0.0f;
    }
  }
  // prologue: stage W_in(0) into buffer 0 (1024 f4 / 512 threads = 2 each)
  {
    const float4* src = (const float4*)(g_win);
#pragma unroll
    for (int r = 0; r < 2; ++r) {
      const int idx = tid + r * 512;
      const int row = idx >> 7, off = idx & 127;
      *(float4*)(s_win + row * SWIN + off * 4) = src[idx];
    }
  }

  float loss_acc = 0.0f;

  for (int i = 0; i < NCB; ++i) {
    __syncthreads();  // orders: prev-D s_res/s_wout use vs A1 reads/stager writes

    if (tid < 128) {
      // ---- A1+A2: in-proj + normalize (waves 0,1). col=tid>>3, o=tid&7:
      // 8 d's of a column in 8 adjacent lanes -> shfl-tree normalize (bitwise
      // == np pairwise-8 tree by IEEE add commutativity; verified).
      // einsum SOP path: single sequential fmaf chain, c ascending (float2).
      const int a_col = tid >> 3, a_o = tid & 7;
      const float2* wr = (const float2*)(s_win + (i & 1) * (8 * SWIN) + a_o * SWIN);
      const float2* rr = (const float2*)(s_res + a_col * SRES);
      float acc = 0.0f;
#pragma unroll 8
      for (int h = 0; h < 256; ++h) {
        const float2 w = wr[h];
        const float2 r = rr[h];
        acc = fmaf(w.x, r.x, acc);
        acc = fmaf(w.y, r.y, acc);
      }
      const float ze = acc + in_b[i * 8 + a_o];  // bias added after (np.add)
      s_ze[a_o * 16 + a_col] = ze;
      const float q = sqf(ze);
      const float t1 = q + __shfl_xor(q, 1);
      const float t2 = t1 + __shfl_xor(t1, 2);
      const float t3 = t2 + __shfl_xor(t2, 4);
      float nrm = sqrtf(t3);
      nrm = fmaxf(nrm, 1e-12f);
      const float en = ze / nrm;                 // IEEE div per element (np)
      s_en[a_o * 16 + a_col] = en;
      const float s2 = sqf(en);
      const float u1 = s2 + __shfl_xor(s2, 1);
      const float u2 = u1 + __shfl_xor(u1, 2);
      const float u3 = u2 + __shfl_xor(u2, 4);
      if (a_o == 0) s_s[a_col] = u3;
    } else {
      // ---- STAGERS (waves 2-7, 384 threads): copy iteration-i tables into
      // padded LDS while A1's serial chain runs. Pure data movement — values
      // bit-identical, only residency changes.
      const int st = tid - 128;  // 0..383
      {  // cbn(i): 2048 f4, 32 grp-rows x 64 f4
        const float4* src = (const float4*)(g_cbn + (size_t)i * (KK * 8));
#pragma unroll
        for (int r = 0; r < 6; ++r) {
          const int idx = st + r * 384;
          if (idx < 2048) {
            const int row = idx >> 6, off = idx & 63;
            *(float4*)(s_cbn + row * SCBN + off * 4) = src[idx];
          }
        }
      }
      if (st < 256) {  // c2(i): 256 f4, 32 rows x 8 f4
        const float4* src = (const float4*)(g_c2 + (size_t)i * KK);
        const int row = st >> 3, off = st & 7;
        *(float4*)(s_c2 + row * SC2 + off * 4) = src[st];
      }
      {  // wout(i): 1024 f4, 32 rows x 32 f4
        const float4* src = (const float4*)(g_wout + (size_t)i * (DIN * 8));
#pragma unroll
        for (int r = 0; r < 3; ++r) {
          const int idx = st + r * 384;
          if (idx < 1024) {
            const int row = idx >> 5, off = idx & 31;
            *(float4*)(s_wout + row * SWO + off * 4) = src[idx];
          }
        }
      }
      if (st < 128) {  // obt(i): 128 f4, 32 rows x 4 f4
        const float4* src = (const float4*)(g_obt + (size_t)i * DIN);
        const int row = st >> 2, off = st & 3;
        *(float4*)(s_obt + row * SOB + off * 4) = src[st];
      }
      if (i + 1 < NCB) {  // W_in(i+1) into buffer (i+1)&1: 1024 f4, 8 rows x 128 f4
        const float4* src = (const float4*)(g_win + (size_t)(i + 1) * (8 * DIN));
        float* dstb = s_win + ((i + 1) & 1) * (8 * SWIN);
#pragma unroll
        for (int r = 0; r < 3; ++r) {
          const int idx = st + r * 384;
          if (idx < 1024) {
            const int row = idx >> 7, off = idx & 127;
            *(float4*)(dstb + row * SWIN + off * 4) = src[idx];
          }
        }
      }
    }
    __syncthreads();  // s_en/s_s ready + staged tables ready

    // ---- B: distance scan, k = 32j+grp per thread — now fed from LDS
    // (16-lane broadcast, grp rows pad-260 -> distinct bank clusters).
    // np: dist = (s - 2*dot) + c2; 2*dot exact, so fmaf(-2,dot,s) == s - dot2.
    {
      const float en0 = s_en[col],      en1 = s_en[16 + col];
      const float en2 = s_en[32 + col], en3 = s_en[48 + col];
      const float en4 = s_en[64 + col], en5 = s_en[80 + col];
      const float en6 = s_en[96 + col], en7 = s_en[112 + col];
      const float sv = s_s[col];
      const float* cp  = s_cbn + grp * SCBN;
      const float* c2p = s_c2  + grp * SC2;
      float dmin = 3.402823466e38f; int jmin = 0;
      for (int jo = 0; jo < 8; ++jo) {
        const float4 c2q = *(const float4*)(c2p + jo * 4);
        const float c2a[4] = {c2q.x, c2q.y, c2q.z, c2q.w};
#pragma unroll
        for (int ji = 0; ji < 4; ++ji) {
          const int j = jo * 4 + ji;
          const float4 c0 = *(const float4*)(cp + j * 8);
          const float4 c1 = *(const float4*)(cp + j * 8 + 4);
          float dot = 0.0f;
          dot = fmaf(en0, c0.x, dot); dot = fmaf(en1, c0.y, dot);
          dot = fmaf(en2, c0.z, dot); dot = fmaf(en3, c0.w, dot);
          dot = fmaf(en4, c1.x, dot); dot = fmaf(en5, c1.y, dot);
          dot = fmaf(en6, c1.z, dot); dot = fmaf(en7, c1.w, dot);
          const float dist = fmaf(-2.0f, dot, sv) + c2a[ji];
          if (dist < dmin) { dmin = dist; jmin = j; }  // strict <, j asc = first-min
        }
      }
      int kmin = (jmin << 5) + grp;
      // in-wave argmin over the wave's 4 grp-subsets (lexicographic (d,k) min
      // is associative+commutative == global first-min rule; verified)
      float od = __shfl_xor(dmin, 16); int ok = __shfl_xor(kmin, 16);
      if (od < dmin || (od == dmin && ok < kmin)) { dmin = od; kmin = ok; }
      od = __shfl_xor(dmin, 32); ok = __shfl_xor(kmin, 32);
      if (od < dmin || (od == dmin && ok < kmin)) { dmin = od; kmin = ok; }
      if ((tid & 48) == 0) {
        s_cd[(tid >> 6) * 16 + col] = dmin;
        s_ck[(tid >> 6) * 16 + col] = kmin;
      }
    }
    __syncthreads();

    // ---- D: per-lane 8-way argmin (redundant, associative => identical),
    // codes from the 16 grp==0 lanes, STE in-register (16-way broadcast cb-row
    // load), out-proj from staged LDS + latent & residual update.
    {
      float bd = s_cd[col]; int bk = s_ck[col];
#pragma unroll
      for (int w = 1; w < 8; ++w) {
        const float d2 = s_cd[w * 16 + col]; const int k2 = s_ck[w * 16 + col];
        if (d2 < bd || (d2 == bd && k2 < bk)) { bd = d2; bk = k2; }
      }
      if (grp == 0)
        out[((size_t)b * NCB + i) * TT + t0 + col] = (float)bk;

      const float* cr = cb + ((size_t)i * KK + bk) * 8;  // RAW codebook row
      const float4 cq0 = *(const float4*)(cr);
      const float4 cq1 = *(const float4*)(cr + 4);
      const float zqa[8] = {cq0.x, cq0.y, cq0.z, cq0.w, cq1.x, cq1.y, cq1.z, cq1.w};
      float qst[8];
#pragma unroll
      for (int d = 0; d < 8; ++d) {
        const float ze = s_ze[d * 16 + col];
        const float zq = zqa[d];
        qst[d] = ze + (zq - ze);                 // STE rounding mirrored
        if (grp == 0) {                          // loss counted once per (d,col)
          const float df = ze - zq;
          loss_acc = fmaf(df, df, loss_acc);     // loss precision uncritical (2% thr)
        }
      }
      const float* gw  = s_wout + grp * SWO;   // 16 j x 8 staged
      const float* obp = s_obt  + grp * SOB;
      for (int jo = 0; jo < 4; ++jo) {
        const float4 obq = *(const float4*)(obp + jo * 4);
        const float oba[4] = {obq.x, obq.y, obq.z, obq.w};
#pragma unroll
        for (int ji = 0; ji < 4; ++ji) {
          const int j = jo * 4 + ji;
          const float4 w0 = *(const float4*)(gw + j * 8);
          const float4 w1 = *(const float4*)(gw + j * 8 + 4);
          float dot = 0.0f;
          dot = fmaf(w0.x, qst[0], dot); dot = fmaf(w0.y, qst[1], dot);
          dot = fmaf(w0.z, qst[2], dot); dot = fmaf(w0.w, qst[3], dot);
          dot = fmaf(w1.x, qst[4], dot); dot = fmaf(w1.y, qst[5], dot);
          dot = fmaf(w1.z, qst[6], dot); dot = fmaf(w1.w, qst[7], dot);
          const float lat = dot + oba[ji];       // einsum + bias (one rounded add)
          lr[j] += lat;                          // latent += lat_i (np per-step f32)
          s_res[col * SRES + grp + (j << 5)] -= lat;  // residual -= lat_i
        }
      }
    }
    // loop-top barrier orders D's s_res/s_wout use vs next A1/stagers.
  }

  // latent output (exact per-step accumulation)
  {
    float* lat = out + OUT_LAT;
#pragma unroll
    for (int j = 0; j < 16; ++j) {
      const int c = grp + (j << 5);
      lat[((size_t)b * DIN + c) * TT + t0 + col] = lr[j];
    }
  }

  // loss reduce (nonzero only lanes 0..15 of wave 0), one atomic per block
  if (tid < 64) {
    float v = loss_acc;
#pragma unroll
    for (int off = 32; off; off >>= 1) v += __shfl_down(v, off);
    if (tid == 0) atomicAdd(&g_loss, (double)v);
  }
}

// ---------- epilogue: finalize scalar losses ----------
__global__ void rvq_epi_k(float* __restrict__ out) {
  const float m = (float)(g_loss / 524288.0);  // B*D_CB*T
  out[OUT_CLOSS]     = m;
  out[OUT_CLOSS + 1] = m;
}

extern "C" void kernel_launch(void* const* d_in, const int* in_sizes, int n_in,
                              void* d_out, int out_size, void* d_ws, size_t ws_size,
                              hipStream_t stream) {
  const float* z     = (const float*)d_in[0];
  const float* in_v  = (const float*)d_in[1];
  const float* in_g  = (const float*)d_in[2];
  const float* in_b  = (const float*)d_in[3];
  const float* out_v = (const float*)d_in[4];
  const float* out_g = (const float*)d_in[5];
  const float* out_b = (const float*)d_in[6];
  const float* cb    = (const float*)d_in[7];
  float* out = (float*)d_out;
  (void)d_ws; (void)ws_size;

  prep_win_k <<<2, 64, 0, stream>>>(in_v, in_g);
  prep_wout_k<<<18, 256, 0, stream>>>(out_v, out_g, out_b);
  prep_cbn_k <<<36, 256, 0, stream>>>(cb);
  rvq_main_k <<<4096, 512, 0, stream>>>(z, in_b, cb, out);
  rvq_epi_k  <<<1, 1, 0, stream>>>(out);
}